// Round 13
// baseline (484.554 us; speedup 1.0000x reference)
//
#include <hip/hip_runtime.h>

#define T_ 16
#define E_ 64
#define V_ 96
#define L_ 4

typedef unsigned int u32;
typedef unsigned short u16;
typedef __attribute__((ext_vector_type(8))) short bf16x8;
typedef __attribute__((ext_vector_type(4))) float f32x4;

#define MFMA(a, b, c) __builtin_amdgcn_mfma_f32_16x16x32_bf16(a, b, c, 0, 0, 0)
#define SCHED_FENCE() __builtin_amdgcn_sched_barrier(0)

// ws layout (bf16/short elements): [n][kslot] per matrix, where the K-slot ->
// input-dim bijection is kperm (matches the natural register layout of the
// transposed activations: lane holds e = f*32 + (i>>2)*16 + qq*4 + (i&3)).
// Both MFMA operands use the same bijection, so it cancels.
#define OFF_TQ 0
#define OFF_TK 16384
#define OFF_TV 32768
#define OFF_TWO 49152
#define OFF_TW1 65536
#define OFF_TW2 81920
#define OFF_TWOUT 98304
#define PREP_TOT 104448

__device__ __forceinline__ int kperm(int k) {  // K-slot -> input dim e
  int f = k >> 5, i = k & 7, qq = (k >> 3) & 3;
  return f * 32 + (i >> 2) * 16 + qq * 4 + (i & 3);
}

__device__ __forceinline__ short f2b_rne(float f) {  // fp32 -> bf16 RNE (prep only)
  u32 u = __float_as_uint(f);
  u32 r = (u + 0x7fffu + ((u >> 16) & 1u)) >> 16;
  return (short)r;
}
__device__ __forceinline__ float b2f(short s) {
  return __uint_as_float(((u32)(u16)s) << 16);
}
// round-half-up bf16 pack: low short = bf16(a), high short = bf16(b). 3 VALU.
__device__ __forceinline__ u32 pack2_ru(float a, float b) {
  return __builtin_amdgcn_perm(__float_as_uint(a) + 0x8000u,
                               __float_as_uint(b) + 0x8000u, 0x03020706u);
}
// f32x4 C-regs -> bf16x8 frag {v0,v1,v2,v3, 0,0,0,0}: same-slot-map trick,
// upper-K zeros contribute nothing (verified structure from r12).
__device__ __forceinline__ bf16x8 pk4z(f32x4 a) {
  union { bf16x8 v; u32 w[4]; } u;
  u.w[0] = pack2_ru(a[0], a[1]);
  u.w[1] = pack2_ru(a[2], a[3]);
  u.w[2] = 0u;
  u.w[3] = 0u;
  return u.v;
}
__device__ __forceinline__ bf16x8 mk8(u32 a, u32 b, u32 c, u32 d) {
  union { bf16x8 v; u32 w[4]; } u;
  u.w[0] = a; u.w[1] = b; u.w[2] = c; u.w[3] = d;
  return u.v;
}

__global__ void __launch_bounds__(256) prep_weights(
    const float* __restrict__ Wq, const float* __restrict__ Wk,
    const float* __restrict__ Wv, const float* __restrict__ Wo,
    const float* __restrict__ W1, const float* __restrict__ W2,
    const float* __restrict__ Wout, short* __restrict__ wpo) {
  int id = blockIdx.x * 256 + threadIdx.x;
  if (id >= PREP_TOT) return;
  float v;
  if (id < OFF_TWO) {                       // TQ/TK/TV: n = h*16+kq, k-slot
    int which = id >> 14;                   // 0=Q,1=K,2=V
    int r = id & 16383;
    int l = r >> 12, n = (r >> 6) & 63, e = kperm(r & 63);
    int h = n >> 4, kq = n & 15;
    const float* W = which == 0 ? Wq : (which == 1 ? Wk : Wv);
    v = W[((l * 4 + h) * 64 + e) * 16 + kq];
  } else if (id < OFF_TWOUT) {              // TWo/TW1/TW2: n = out col, k-slot
    int id2 = id - OFF_TWO;
    int which = id2 >> 14;                  // 0=Wo,1=W1,2=W2
    int r = id2 & 16383;
    int l = r >> 12, n = (r >> 6) & 63, e = kperm(r & 63);
    const float* W = which == 0 ? Wo : (which == 1 ? W1 : W2);
    v = W[(l * 64 + e) * 64 + n];
  } else {                                  // TWout: n = vocab col, k-slot
    int r = id - OFF_TWOUT;
    int n = r >> 6, e = kperm(r & 63);
    v = Wout[e * 96 + n];
  }
  wpo[id] = f2b_rne(v);
}

// LayerNorm over 64 e-values of ONE token held per lane as vals[4 tiles][4 r]
// (e = 16*T + 4*qq + r). In-lane sum of 16 + cross-qq via shfl_xor 16/32.
__device__ __forceinline__ void ln64(float vals[4][4]) {
  float sm = 0.f;
#pragma unroll
  for (int t = 0; t < 4; ++t)
#pragma unroll
    for (int r = 0; r < 4; ++r) sm += vals[t][r];
  sm += __shfl_xor(sm, 16); sm += __shfl_xor(sm, 32);
  float mean = sm * 0.015625f;
  float s2 = 0.f;
#pragma unroll
  for (int t = 0; t < 4; ++t)
#pragma unroll
    for (int r = 0; r < 4; ++r) { float d = vals[t][r] - mean; s2 = fmaf(d, d, s2); }
  s2 += __shfl_xor(s2, 16); s2 += __shfl_xor(s2, 32);
  float rst = rsqrtf(s2 * 0.015625f + 1e-5f);
#pragma unroll
  for (int t = 0; t < 4; ++t)
#pragma unroll
    for (int r = 0; r < 4; ++r) vals[t][r] = (vals[t][r] - mean) * rst;
}

// LDS-FREE kernel (r13). r12's transpose-free structure, but all activations
// (x, o, x1, h1) stay in REGISTERS between matmuls: the prep kernel stores
// every weight with the kperm K-slot bijection that matches the natural
// register layout of the transposed outputs, so C-layout results pack
// directly into the next B-fragment (pack2_ru pairs). Zero __shared__; no
// ds_write/ds_read/lgkmcnt on the critical path; embedding loads per-lane in
// the register layout. LN per-token in-lane + shfl crossbar. 2 seqs/wave
// (ILP chains), 4 waves/block, (256,3) budget ~170 unified regs (r9 model).
__global__ void __launch_bounds__(256, 3) bert_mfma(
    const int* __restrict__ data,
    const float* __restrict__ tok_emb, const float* __restrict__ pos_emb,
    const float* __restrict__ bo, const float* __restrict__ ln1g,
    const float* __restrict__ ln1b, const float* __restrict__ ln2g,
    const float* __restrict__ ln2b, const float* __restrict__ b1,
    const float* __restrict__ b2, const float* __restrict__ bout,
    const short* __restrict__ wp, float* __restrict__ out) {
  const int w = threadIdx.x >> 6;
  const int lane = threadIdx.x & 63;
  const int m = lane & 15;   // token (col of transposed outputs / frag row)
  const int qq = lane >> 4;  // K-chunk / C-row group
  const int seq0 = blockIdx.x * 8 + w * 2;

  const short s1b = (short)0x3F80;
  const bf16x8 ones8 = {s1b, s1b, s1b, s1b, s1b, s1b, s1b, s1b};
  const f32x4 z4 = {0.f, 0.f, 0.f, 0.f};

  bf16x8 ax0[2], ax1[2];   // x as frags (B or A operand), kperm layout
  float xres[2][4][4];     // residual stream fp32: xres[s][T][r] = x[m][16T+4qq+r]

  // ---- embedding: per-lane loads directly in the register layout ----
#pragma unroll
  for (int s = 0; s < 2; ++s) {
    const int tok = data[(seq0 + s) * T_ + m];
    u32 xw[8];
#pragma unroll
    for (int T = 0; T < 4; ++T) {
      float4 te = *(const float4*)(tok_emb + tok * E_ + T * 16 + qq * 4);
      float4 pe = *(const float4*)(pos_emb + m * E_ + T * 16 + qq * 4);
      u32 lo = pack2_ru(te.x + pe.x, te.y + pe.y);
      u32 hi = pack2_ru(te.z + pe.z, te.w + pe.w);
      xw[T * 2] = lo; xw[T * 2 + 1] = hi;
      xres[s][T][0] = b2f((short)(lo & 0xffffu));
      xres[s][T][1] = b2f((short)(lo >> 16));
      xres[s][T][2] = b2f((short)(hi & 0xffffu));
      xres[s][T][3] = b2f((short)(hi >> 16));
    }
    ax0[s] = mk8(xw[0], xw[1], xw[2], xw[3]);
    ax1[s] = mk8(xw[4], xw[5], xw[6], xw[7]);
  }

#pragma unroll 1
  for (int l = 0; l < L_; ++l) {
    const short* TQ = wp + OFF_TQ + l * 4096;
    const short* TK = wp + OFF_TK + l * 4096;
    const short* TV = wp + OFF_TV + l * 4096;
    const short* TWO = wp + OFF_TWO + l * 4096;
    const short* TW1 = wp + OFF_TW1 + l * 4096;
    const short* TW2 = wp + OFF_TW2 + l * 4096;

    // ---- attention, fully in registers; o accumulates into frag words ----
    u32 ow[2][8];
#pragma unroll
    for (int h = 0; h < 4; ++h) {
      const int bn = (h * 16 + m) * 64 + qq * 8;
      bf16x8 wq0 = *(const bf16x8*)(TQ + bn), wq1 = *(const bf16x8*)(TQ + bn + 32);
      bf16x8 wk0 = *(const bf16x8*)(TK + bn), wk1 = *(const bf16x8*)(TK + bn + 32);
      bf16x8 wv0 = *(const bf16x8*)(TV + bn), wv1 = *(const bf16x8*)(TV + bn + 32);
#pragma unroll
      for (int s = 0; s < 2; ++s) {
        // qT[kq][t], kT[kq][t] (lane=t); v[t][kd] (lane=kd)
        f32x4 qT = MFMA(wq0, ax0[s], z4); qT = MFMA(wq1, ax1[s], qT);
        f32x4 kT = MFMA(wk0, ax0[s], z4); kT = MFMA(wk1, ax1[s], kT);
        f32x4 vv = MFMA(ax0[s], wv0, z4); vv = MFMA(ax1[s], wv1, vv);
        bf16x8 qpk = pk4z(qT), kpk = pk4z(kT), vpk = pk4z(vv);
        f32x4 sT = MFMA(kpk, qpk, z4);     // S^T, K=16 real + zero pad
        f32x4 ev;
#pragma unroll
        for (int r = 0; r < 4; ++r) ev[r] = __expf(sT[r] * 0.25f);
        bf16x8 ppk = pk4z(ev);
        f32x4 oT = MFMA(vpk, ppk, z4);     // O^T[kd][t], lane=t, regs=kd
        f32x4 rs = MFMA(ones8, ppk, z4);   // full 16-key rowsum
        float inv = __builtin_amdgcn_rcpf(rs[0]);
        // head h -> frag h>>1, words (h&1)*2 + {0,1}: e = h*16 + 4qq + r
        ow[s][(h >> 1) * 4 + (h & 1) * 2 + 0] = pack2_ru(oT[0] * inv, oT[1] * inv);
        ow[s][(h >> 1) * 4 + (h & 1) * 2 + 1] = pack2_ru(oT[2] * inv, oT[3] * inv);
      }
    }
    bf16x8 ao0[2], ao1[2];
#pragma unroll
    for (int s = 0; s < 2; ++s) {
      ao0[s] = mk8(ow[s][0], ow[s][1], ow[s][2], ow[s][3]);
      ao1[s] = mk8(ow[s][4], ow[s][5], ow[s][6], ow[s][7]);
    }
    SCHED_FENCE();

    // ---- phase 7: x1 = LN1(x + o@Wo + bo); o feeds straight from regs ----
    {
#pragma unroll
      for (int t = 0; t < 4; ++t) {
        const int bn = (t * 16 + m) * 64 + qq * 8;
        bf16x8 w0 = *(const bf16x8*)(TWO + bn), w1 = *(const bf16x8*)(TWO + bn + 32);
        float4 bc = *(const float4*)(bo + l * E_ + t * 16 + qq * 4);
#pragma unroll
        for (int s = 0; s < 2; ++s) {
          f32x4 d = MFMA(w0, ao0[s], z4); d = MFMA(w1, ao1[s], d);
          xres[s][t][0] += d[0] + bc.x; xres[s][t][1] += d[1] + bc.y;
          xres[s][t][2] += d[2] + bc.z; xres[s][t][3] += d[3] + bc.w;
        }
      }
#pragma unroll
      for (int s = 0; s < 2; ++s) ln64(xres[s]);
      u32 xw[2][8];
#pragma unroll
      for (int t = 0; t < 4; ++t) {
        float4 g4 = *(const float4*)(ln1g + l * E_ + t * 16 + qq * 4);
        float4 b4 = *(const float4*)(ln1b + l * E_ + t * 16 + qq * 4);
#pragma unroll
        for (int s = 0; s < 2; ++s) {
          float x0 = fmaf(xres[s][t][0], g4.x, b4.x);
          float x1v = fmaf(xres[s][t][1], g4.y, b4.y);
          float x2 = fmaf(xres[s][t][2], g4.z, b4.z);
          float x3 = fmaf(xres[s][t][3], g4.w, b4.w);
          xres[s][t][0] = x0; xres[s][t][1] = x1v;
          xres[s][t][2] = x2; xres[s][t][3] = x3;
          xw[s][t * 2] = pack2_ru(x0, x1v);
          xw[s][t * 2 + 1] = pack2_ru(x2, x3);
        }
      }
#pragma unroll
      for (int s = 0; s < 2; ++s) {
        ax0[s] = mk8(xw[s][0], xw[s][1], xw[s][2], xw[s][3]);
        ax1[s] = mk8(xw[s][4], xw[s][5], xw[s][6], xw[s][7]);
      }
    }
    SCHED_FENCE();

    // ---- phase 8: h1 = relu(x1@W1 + b1) -> frag words ----
    bf16x8 ah0[2], ah1[2];
    {
      u32 hw[2][8];
#pragma unroll
      for (int t = 0; t < 4; ++t) {
        const int bn = (t * 16 + m) * 64 + qq * 8;
        bf16x8 w0 = *(const bf16x8*)(TW1 + bn), w1 = *(const bf16x8*)(TW1 + bn + 32);
        float4 bc = *(const float4*)(b1 + l * E_ + t * 16 + qq * 4);
#pragma unroll
        for (int s = 0; s < 2; ++s) {
          f32x4 acc = MFMA(w0, ax0[s], z4); acc = MFMA(w1, ax1[s], acc);
          float h0 = fmaxf(acc[0] + bc.x, 0.f), h1v = fmaxf(acc[1] + bc.y, 0.f);
          float h2 = fmaxf(acc[2] + bc.z, 0.f), h3 = fmaxf(acc[3] + bc.w, 0.f);
          hw[s][t * 2] = pack2_ru(h0, h1v);
          hw[s][t * 2 + 1] = pack2_ru(h2, h3);
        }
      }
#pragma unroll
      for (int s = 0; s < 2; ++s) {
        ah0[s] = mk8(hw[s][0], hw[s][1], hw[s][2], hw[s][3]);
        ah1[s] = mk8(hw[s][4], hw[s][5], hw[s][6], hw[s][7]);
      }
    }
    SCHED_FENCE();

    // ---- phase 9: x = LN2(x1 + h1@W2 + b2) -> frag words (next layer) ----
    {
#pragma unroll
      for (int t = 0; t < 4; ++t) {
        const int bn = (t * 16 + m) * 64 + qq * 8;
        bf16x8 w0 = *(const bf16x8*)(TW2 + bn), w1 = *(const bf16x8*)(TW2 + bn + 32);
        float4 bc = *(const float4*)(b2 + l * E_ + t * 16 + qq * 4);
#pragma unroll
        for (int s = 0; s < 2; ++s) {
          f32x4 d = MFMA(w0, ah0[s], z4); d = MFMA(w1, ah1[s], d);
          xres[s][t][0] += d[0] + bc.x; xres[s][t][1] += d[1] + bc.y;
          xres[s][t][2] += d[2] + bc.z; xres[s][t][3] += d[3] + bc.w;
        }
      }
#pragma unroll
      for (int s = 0; s < 2; ++s) ln64(xres[s]);
      u32 xw[2][8];
#pragma unroll
      for (int t = 0; t < 4; ++t) {
        float4 g4 = *(const float4*)(ln2g + l * E_ + t * 16 + qq * 4);
        float4 b4 = *(const float4*)(ln2b + l * E_ + t * 16 + qq * 4);
#pragma unroll
        for (int s = 0; s < 2; ++s) {
          float x0 = fmaf(xres[s][t][0], g4.x, b4.x);
          float x1v = fmaf(xres[s][t][1], g4.y, b4.y);
          float x2 = fmaf(xres[s][t][2], g4.z, b4.z);
          float x3 = fmaf(xres[s][t][3], g4.w, b4.w);
          xres[s][t][0] = x0; xres[s][t][1] = x1v;
          xres[s][t][2] = x2; xres[s][t][3] = x3;
          xw[s][t * 2] = pack2_ru(x0, x1v);
          xw[s][t * 2 + 1] = pack2_ru(x2, x3);
        }
      }
#pragma unroll
      for (int s = 0; s < 2; ++s) {
        ax0[s] = mk8(xw[s][0], xw[s][1], xw[s][2], xw[s][3]);
        ax1[s] = mk8(xw[s][4], xw[s][5], xw[s][6], xw[s][7]);
      }
    }
    SCHED_FENCE();
  }

  // ---- epilogue: logits tiles = mfma(A=TWOUT, B=x-frags); float4 stores ----
  {
    const short* TWOUT = wp + OFF_TWOUT;
#pragma unroll 1
    for (int t = 0; t < 6; ++t) {
      const int bn = (t * 16 + m) * 64 + qq * 8;
      bf16x8 w0 = *(const bf16x8*)(TWOUT + bn), w1 = *(const bf16x8*)(TWOUT + bn + 32);
      float4 bc = *(const float4*)(bout + t * 16 + qq * 4);
#pragma unroll
      for (int s = 0; s < 2; ++s) {
        f32x4 acc = MFMA(w0, ax0[s], z4); acc = MFMA(w1, ax1[s], acc);
        float4 o4 = make_float4(acc[0] + bc.x, acc[1] + bc.y,
                                acc[2] + bc.z, acc[3] + bc.w);
        *(float4*)&out[((seq0 + s) * T_ + m) * V_ + t * 16 + qq * 4] = o4;
      }
    }
  }
}

extern "C" void kernel_launch(void* const* d_in, const int* in_sizes, int n_in,
                              void* d_out, int out_size, void* d_ws, size_t ws_size,
                              hipStream_t stream) {
  const int*   data    = (const int*)d_in[0];
  const float* tok_emb = (const float*)d_in[1];
  const float* pos_emb = (const float*)d_in[2];
  const float* Wq      = (const float*)d_in[3];
  const float* Wk      = (const float*)d_in[4];
  const float* Wv      = (const float*)d_in[5];
  const float* Wo      = (const float*)d_in[6];
  const float* bo      = (const float*)d_in[7];
  const float* ln1g    = (const float*)d_in[8];
  const float* ln1b    = (const float*)d_in[9];
  const float* ln2g    = (const float*)d_in[10];
  const float* ln2b    = (const float*)d_in[11];
  const float* W1      = (const float*)d_in[12];
  const float* b1      = (const float*)d_in[13];
  const float* W2      = (const float*)d_in[14];
  const float* b2      = (const float*)d_in[15];
  const float* Wout    = (const float*)d_in[16];
  const float* bout    = (const float*)d_in[17];
  float* out = (float*)d_out;
  short* wp = (short*)d_ws;  // 104448*2 = 208896 B of workspace

  prep_weights<<<(PREP_TOT + 255) / 256, 256, 0, stream>>>(
      Wq, Wk, Wv, Wo, W1, W2, Wout, wp);

  const int B = in_sizes[0] / T_;  // 16384 sequences, 8 per block (2 per wave)
  bert_mfma<<<B / 8, 256, 0, stream>>>(data, tok_emb, pos_emb, bo, ln1g, ln1b,
                                       ln2g, ln2b, b1, b2, bout, wp, out);
}